// Round 7
// baseline (366.998 us; speedup 1.0000x reference)
//
#include <hip/hip_runtime.h>
#include <cstdint>
#include <cstddef>

#define D 128

typedef unsigned short ushort_t;
typedef unsigned int uint_t;
typedef __attribute__((ext_vector_type(8))) short bf16x8;
typedef __attribute__((ext_vector_type(4))) float f32x4;

static __device__ __forceinline__ unsigned short f2bf(float f) {
    unsigned int u = __float_as_uint(f);
    u = (u + 0x7FFFu + ((u >> 16) & 1u)) >> 16;  // RNE
    return (unsigned short)u;
}
static __device__ __forceinline__ float bf_lo(uint_t v) {
    return __uint_as_float(v << 16);
}
static __device__ __forceinline__ float bf_hi(uint_t v) {
    return __uint_as_float(v & 0xFFFF0000u);
}

static __device__ __forceinline__ void cast8(const float* __restrict__ s,
                                             ushort_t* __restrict__ d) {
    float4 a = *(const float4*)s;
    float4 b = *(const float4*)(s + 4);
    uint4 o;
    o.x = (uint_t)f2bf(a.x) | ((uint_t)f2bf(a.y) << 16);
    o.y = (uint_t)f2bf(a.z) | ((uint_t)f2bf(a.w) << 16);
    o.z = (uint_t)f2bf(b.x) | ((uint_t)f2bf(b.y) << 16);
    o.w = (uint_t)f2bf(b.z) | ((uint_t)f2bf(b.w) << 16);
    *(uint4*)d = o;
}

// ================= fused front-end: bkt_hist + cast_x + cast_w =================

__global__ __launch_bounds__(256) void front_fused(
    const int* __restrict__ dst, int* __restrict__ bhist, int E, int EB,
    const float* __restrict__ x, ushort_t* __restrict__ xb, long nx, int CX,
    const float* __restrict__ W1l, const float* __restrict__ W1r,
    const float* __restrict__ W2l, const float* __restrict__ W2r,
    ushort_t* __restrict__ W1lb, ushort_t* __restrict__ W1rb,
    ushort_t* __restrict__ W2lb, ushort_t* __restrict__ W2rb) {
    __shared__ int lh[512];
    int b = blockIdx.x, t = threadIdx.x;
    if (b < EB) {
        lh[t] = 0;
        lh[t + 256] = 0;
        __syncthreads();
        int base = b * 4096;
#pragma unroll
        for (int i = 0; i < 16; ++i) {
            int e = base + i * 256 + t;
            if (e < E) atomicAdd(&lh[dst[e] >> 8], 1);
        }
        __syncthreads();
        if (lh[t]) atomicAdd(&bhist[t], lh[t]);
        if (lh[t + 256]) atomicAdd(&bhist[t + 256], lh[t + 256]);
    } else if (b < EB + CX) {
        long i = ((long)(b - EB) * 256 + t) * 8;
        if (i < nx) cast8(x + i, xb + i);
    } else {
        int bb = b - EB - CX;  // 0..31; 8 blocks per weight array
        int arr = bb >> 3;
        long i = ((long)(bb & 7) * 256 + t) * 8;
        const float* s = (arr == 0) ? W1l : (arr == 1) ? W1r
                       : (arr == 2) ? W2l : W2r;
        ushort_t* d = (arr == 0) ? W1lb : (arr == 1) ? W1rb
                    : (arr == 2) ? W2lb : W2rb;
        cast8(s + i, d + i);
    }
}

// ================= CSR build =================

__global__ __launch_bounds__(512) void bkt_scan(const int* __restrict__ bhist,
                                                int* __restrict__ boff,
                                                int* __restrict__ bcur,
                                                int* __restrict__ row_ptr,
                                                int N, int E) {
    __shared__ int s[512];
    int t = threadIdx.x;
    int v = bhist[t];
    s[t] = v;
    __syncthreads();
    for (int off = 1; off < 512; off <<= 1) {
        int u = (t >= off) ? s[t - off] : 0;
        __syncthreads();
        s[t] += u;
        __syncthreads();
    }
    int ex = s[t] - v;
    boff[t] = ex;
    bcur[t] = ex;
    if (t == 511) boff[512] = s[511];
    if (t == 0) row_ptr[N] = E;
}

__global__ __launch_bounds__(256) void bkt_scatter(const int* __restrict__ src,
                                                   const int* __restrict__ dst,
                                                   int* __restrict__ bcur,
                                                   int* __restrict__ ebuf, int E) {
    __shared__ int lh[512];
    __shared__ int lofs[512];
    __shared__ int gb[512];
    __shared__ int sv[4096];
    __shared__ unsigned short sb[4096];
    int t = threadIdx.x;
    lh[t] = 0;
    lh[t + 256] = 0;
    __syncthreads();
    int base = blockIdx.x * 4096;
    unsigned pk[16];  // rank<<17 | bkt<<8 | dlocal
#pragma unroll
    for (int i = 0; i < 16; ++i) {
        int e = base + i * 256 + t;
        unsigned p = 0xFFFFFFFFu;
        if (e < E) {
            int d = dst[e];
            int bkt = d >> 8;
            int r = atomicAdd(&lh[bkt], 1);
            p = ((unsigned)r << 17) | ((unsigned)bkt << 8) | (unsigned)(d & 255);
        }
        pk[i] = p;
    }
    __syncthreads();
    int a0 = lh[2 * t], a1 = lh[2 * t + 1];
    int ps = a0 + a1;
    gb[t] = ps;
    __syncthreads();
    for (int off = 1; off < 256; off <<= 1) {
        int u = (t >= off) ? gb[t - off] : 0;
        __syncthreads();
        gb[t] += u;
        __syncthreads();
    }
    int inc = gb[t];
    int exb = inc - ps;
    __syncthreads();
    lofs[2 * t] = exb;
    lofs[2 * t + 1] = exb + a0;
    if (a0) gb[2 * t] = atomicAdd(&bcur[2 * t], a0);
    if (a1) gb[2 * t + 1] = atomicAdd(&bcur[2 * t + 1], a1);
    __syncthreads();
#pragma unroll
    for (int i = 0; i < 16; ++i) {
        int e = base + i * 256 + t;
        if (e < E) {
            unsigned p = pk[i];
            int bkt = (p >> 8) & 511;
            int r = (int)(p >> 17);
            int pos = lofs[bkt] + r;
            sv[pos] = src[e] | ((int)(p & 255) << 20);
            sb[pos] = (unsigned short)bkt;
        }
    }
    __syncthreads();
    int cnt = min(E - base, 4096);
    for (int i = t; i < cnt; i += 256) {
        int b2 = sb[i];
        ebuf[gb[b2] + (i - lofs[b2])] = sv[i];
    }
}

__global__ __launch_bounds__(256) void bkt_build(const int* __restrict__ ebuf,
                                                 const int* __restrict__ boff,
                                                 int* __restrict__ row_ptr,
                                                 int* __restrict__ csr, int N) {
    __shared__ int lcnt[256];
    __shared__ int lofs[256];
    __shared__ int lcur[256];
    int t = threadIdx.x;
    int b = blockIdx.x;
    int base = b << 8;
    int ebeg = boff[b], eend = boff[b + 1];
    lcnt[t] = 0;
    __syncthreads();
    for (int e = ebeg + t; e < eend; e += 256)
        atomicAdd(&lcnt[((unsigned)ebuf[e]) >> 20], 1);
    __syncthreads();
    int v = lcnt[t];
    lofs[t] = v;
    __syncthreads();
    for (int off = 1; off < 256; off <<= 1) {
        int u = (t >= off) ? lofs[t - off] : 0;
        __syncthreads();
        lofs[t] += u;
        __syncthreads();
    }
    int ex = lofs[t] - v;
    __syncthreads();
    lofs[t] = ex;
    lcur[t] = 0;
    if (base + t < N) row_ptr[base + t] = ebeg + ex;
    __syncthreads();
    for (int e = ebeg + t; e < eend; e += 256) {
        int u = ebuf[e];
        int d = ((unsigned)u) >> 20;
        int r = atomicAdd(&lcur[d], 1);
        csr[ebeg + lofs[d] + r] = u & 0xFFFFF;
    }
}

// ================= mean aggregation: 2 nodes per wave, chains interleaved ====
// Node-boundary latency legs (row_ptr -> csr -> gathers) of one node hide
// under the other's gathers; 8 uint4 in flight per wave.

static __device__ __forceinline__ void acc8(uint4 v, float a[8]) {
    a[0] += bf_lo(v.x); a[1] += bf_hi(v.x);
    a[2] += bf_lo(v.y); a[3] += bf_hi(v.y);
    a[4] += bf_lo(v.z); a[5] += bf_hi(v.z);
    a[6] += bf_lo(v.w); a[7] += bf_hi(v.w);
}

static __device__ __forceinline__ uint4 grow(const ushort_t* __restrict__ xin,
                                             int s, int l16) {
    unsigned off = ((unsigned)s << 8) | ((unsigned)l16 << 4);  // bytes
    return *(const uint4*)((const char*)xin + off);
}

static __device__ __forceinline__ void agg_store(ushort_t* __restrict__ aggb,
                                                 int node, int l16,
                                                 const float a[8], int deg) {
    float inv = 1.0f / fmaxf((float)deg, 1.0f);
    uint4 o;
    o.x = (uint_t)f2bf(a[0] * inv) | ((uint_t)f2bf(a[1] * inv) << 16);
    o.y = (uint_t)f2bf(a[2] * inv) | ((uint_t)f2bf(a[3] * inv) << 16);
    o.z = (uint_t)f2bf(a[4] * inv) | ((uint_t)f2bf(a[5] * inv) << 16);
    o.w = (uint_t)f2bf(a[6] * inv) | ((uint_t)f2bf(a[7] * inv) << 16);
    unsigned off = ((unsigned)node << 8) | ((unsigned)l16 << 4);
    *(uint4*)((char*)aggb + off) = o;
}

static __device__ __forceinline__ void agg_body(int bid, int base, int cnt,
                                                const ushort_t* __restrict__ xin,
                                                const int* __restrict__ csr,
                                                const int* __restrict__ row_ptr,
                                                ushort_t* __restrict__ aggb) {
    int wave = threadIdx.x >> 6;
    int lane = threadIdx.x & 63;
    int g = lane >> 4;    // row group 0..3
    int l16 = lane & 15;  // 16B segment within a 256B row
    int p = bid * 8 + wave * 2;
    if (p >= cnt) return;
    int node0 = base + p;
    int node1 = base + min(p + 1, cnt - 1);  // tail: duplicates node0 (benign)
    int b0 = row_ptr[node0];
    int deg0 = row_ptr[node0 + 1] - b0;
    int b1 = row_ptr[node1];
    int deg1 = row_ptr[node1 + 1] - b1;
    int d0 = min(deg0, 64), d1 = min(deg1, 64);
    int i0 = (deg0 > 0) ? csr[b0 + min(lane, deg0 - 1)] : 0;
    int i1 = (deg1 > 0) ? csr[b1 + min(lane, deg1 - 1)] : 0;
    int c0 = max(d0 - 1, 0), c1 = max(d1 - 1, 0);
    float a0[8] = {0.f, 0.f, 0.f, 0.f, 0.f, 0.f, 0.f, 0.f};
    float a1[8] = {0.f, 0.f, 0.f, 0.f, 0.f, 0.f, 0.f, 0.f};
    int mm = max(d0, d1);
    for (int e = 0; e < mm; e += 16) {
        bool do0 = (e < d0), do1 = (e < d1);  // wave-uniform
        uint4 v0[4], v1[4];
        if (do0) {
#pragma unroll
            for (int q = 0; q < 4; ++q) {
                int s = __shfl(i0, min(e + 4 * q + g, c0));
                v0[q] = grow(xin, s, l16);
            }
        }
        if (do1) {
#pragma unroll
            for (int q = 0; q < 4; ++q) {
                int s = __shfl(i1, min(e + 4 * q + g, c1));
                v1[q] = grow(xin, s, l16);
            }
        }
        if (do0) {
#pragma unroll
            for (int q = 0; q < 4; ++q)
                if (e + 4 * q + g < d0) acc8(v0[q], a0);
        }
        if (do1) {
#pragma unroll
            for (int q = 0; q < 4; ++q)
                if (e + 4 * q + g < d1) acc8(v1[q], a1);
        }
    }
    for (int e2 = 64; e2 < deg0; e2 += 4) {  // rare deg>64 fallback
        int s = csr[b0 + min(e2 + g, deg0 - 1)];
        uint4 v = grow(xin, s, l16);
        if (e2 + g < deg0) acc8(v, a0);
    }
    for (int e2 = 64; e2 < deg1; e2 += 4) {
        int s = csr[b1 + min(e2 + g, deg1 - 1)];
        uint4 v = grow(xin, s, l16);
        if (e2 + g < deg1) acc8(v, a1);
    }
#pragma unroll
    for (int i = 0; i < 8; ++i) {
        a0[i] += __shfl_xor(a0[i], 16);
        a1[i] += __shfl_xor(a1[i], 16);
        a0[i] += __shfl_xor(a0[i], 32);
        a1[i] += __shfl_xor(a1[i], 32);
    }
    if (g == 0) {
        agg_store(aggb, node0, l16, a0, deg0);
        agg_store(aggb, node1, l16, a1, deg1);
    }
}

__global__ __launch_bounds__(256) void agg_k(const ushort_t* __restrict__ xin,
                                             const int* __restrict__ csr,
                                             const int* __restrict__ row_ptr,
                                             ushort_t* __restrict__ aggb,
                                             int base, int cnt) {
    agg_body(blockIdx.x, base, cnt, xin, csr, row_ptr, aggb);
}

// ================= MFMA GEMM (R1-proven math, row-base parameterized) ========

static __device__ __forceinline__ void gemm_body(int tile, int rbase,
                                                 const ushort_t* __restrict__ Aagg,
                                                 const ushort_t* __restrict__ Ax,
                                                 const ushort_t* __restrict__ Wl,
                                                 const ushort_t* __restrict__ Wr,
                                                 const float* __restrict__ bias,
                                                 ushort_t* __restrict__ out_bf,
                                                 float* __restrict__ out_f32,
                                                 int N, int relu_bf) {
    __shared__ ushort_t sA[128 * 32];  // 8 KB
    __shared__ ushort_t sW[128 * 32];  // 8 KB
    int tid = threadIdx.x;
    int wave = tid >> 6, lane = tid & 63;
    int quad = lane >> 4, l15 = lane & 15;
    int wm = wave & 1, wc = wave >> 1;
    int n0 = rbase + tile * 128;
    int sr = tid >> 2;
    int sseg = (tid & 3) * 8;

    f32x4 acc[4][4];
#pragma unroll
    for (int mt = 0; mt < 4; ++mt)
#pragma unroll
        for (int nt = 0; nt < 4; ++nt) acc[mt][nt] = (f32x4){0.f, 0.f, 0.f, 0.f};

    int ga0 = min(n0 + sr, N - 1);
    int ga1 = min(n0 + sr + 64, N - 1);

#pragma unroll
    for (int c = 0; c < 8; ++c) {
        const ushort_t* Ab = (c < 4) ? Aagg : Ax;
        const ushort_t* Wb = (c < 4) ? Wl : Wr;
        int koff = (c & 3) * 32 + sseg;
        bf16x8 va0 = *(const bf16x8*)(Ab + (size_t)ga0 * D + koff);
        bf16x8 va1 = *(const bf16x8*)(Ab + (size_t)ga1 * D + koff);
        bf16x8 vw0 = *(const bf16x8*)(Wb + (size_t)sr * D + koff);
        bf16x8 vw1 = *(const bf16x8*)(Wb + (size_t)(sr + 64) * D + koff);
        __syncthreads();
        *(bf16x8*)&sA[sr * 32 + sseg] = va0;
        *(bf16x8*)&sA[(sr + 64) * 32 + sseg] = va1;
        *(bf16x8*)&sW[sr * 32 + sseg] = vw0;
        *(bf16x8*)&sW[(sr + 64) * 32 + sseg] = vw1;
        __syncthreads();

        bf16x8 af[4], wf[4];
#pragma unroll
        for (int mt = 0; mt < 4; ++mt)
            af[mt] = *(const bf16x8*)&sA[(wm * 64 + mt * 16 + l15) * 32 + quad * 8];
#pragma unroll
        for (int nt = 0; nt < 4; ++nt)
            wf[nt] = *(const bf16x8*)&sW[(wc * 64 + nt * 16 + l15) * 32 + quad * 8];
#pragma unroll
        for (int mt = 0; mt < 4; ++mt)
#pragma unroll
            for (int nt = 0; nt < 4; ++nt)
                acc[mt][nt] = __builtin_amdgcn_mfma_f32_16x16x32_bf16(
                    af[mt], wf[nt], acc[mt][nt], 0, 0, 0);
    }

#pragma unroll
    for (int mt = 0; mt < 4; ++mt) {
#pragma unroll
        for (int nt = 0; nt < 4; ++nt) {
            int col = wc * 64 + nt * 16 + l15;
            float bv = bias[col];
#pragma unroll
            for (int reg = 0; reg < 4; ++reg) {
                int row = n0 + wm * 64 + mt * 16 + quad * 4 + reg;
                if (row < N) {
                    float v = acc[mt][nt][reg] + bv;
                    if (relu_bf) {
                        v = fmaxf(v, 0.f);
                        out_bf[(size_t)row * D + col] = f2bf(v);
                    } else {
                        out_f32[(size_t)row * D + col] = v;
                    }
                }
            }
        }
    }
}

__global__ __launch_bounds__(256) void gemm_k(const ushort_t* __restrict__ Aagg,
                                              const ushort_t* __restrict__ Ax,
                                              const ushort_t* __restrict__ Wl,
                                              const ushort_t* __restrict__ Wr,
                                              const float* __restrict__ bias,
                                              ushort_t* __restrict__ out_bf,
                                              float* __restrict__ out_f32,
                                              int rbase, int N, int relu_bf) {
    gemm_body(blockIdx.x, rbase, Aagg, Ax, Wl, Wr, bias, out_bf, out_f32, N, relu_bf);
}

// mid-stage: agg of rows [H,N) co-scheduled with gemm of rows [0,H).
// No intra-kernel dependency: gemm reads aggb[0,H) (written by previous
// kernel); agg writes aggb[H,N) (read by next kernel).
__global__ __launch_bounds__(256) void mid_fused(
    const ushort_t* __restrict__ xin, const int* __restrict__ csr,
    const int* __restrict__ row_ptr, ushort_t* __restrict__ aggb,
    const ushort_t* __restrict__ Wl, const ushort_t* __restrict__ Wr,
    const float* __restrict__ bias, ushort_t* __restrict__ out_bf,
    float* __restrict__ out_f32, int H, int N, int relu_bf, int aggBlocks) {
    if ((int)blockIdx.x < aggBlocks) {
        agg_body(blockIdx.x, H, N - H, xin, csr, row_ptr, aggb);
    } else {
        gemm_body(blockIdx.x - aggBlocks, 0, aggb, xin, Wl, Wr, bias,
                  out_bf, out_f32, N, relu_bf);
    }
}

// ================= launch =================

extern "C" void kernel_launch(void* const* d_in, const int* in_sizes, int n_in,
                              void* d_out, int out_size, void* d_ws, size_t ws_size,
                              hipStream_t stream) {
    const float* x   = (const float*)d_in[0];
    const int*   ei  = (const int*)d_in[1];
    const float* W1l = (const float*)d_in[2];
    const float* b1  = (const float*)d_in[3];
    const float* W1r = (const float*)d_in[4];
    const float* W2l = (const float*)d_in[5];
    const float* b2  = (const float*)d_in[6];
    const float* W2r = (const float*)d_in[7];
    float* out = (float*)d_out;

    int N = in_sizes[0] / D;
    int E = in_sizes[1] / 2;
    const int* src = ei;
    const int* dst = ei + E;

    char* ws = (char*)d_ws;
    size_t off = 0;
    auto take = [&](size_t bytes) -> char* {
        char* p = ws + off;
        off += (bytes + 255) & ~(size_t)255;
        return p;
    };
    int*      row_ptr = (int*)take((size_t)(N + 1) * sizeof(int));
    int*      bhist   = (int*)take((size_t)(512 + 512 + 513) * sizeof(int));
    int*      bcur    = bhist + 512;
    int*      boff    = bhist + 1024;
    int*      ebuf    = (int*)take((size_t)E * sizeof(int));
    int*      csr     = (int*)take((size_t)E * sizeof(int));
    ushort_t* xb      = (ushort_t*)take((size_t)N * D * sizeof(ushort_t));
    ushort_t* hb      = (ushort_t*)take((size_t)N * D * sizeof(ushort_t));
    ushort_t* aggb    = (ushort_t*)take((size_t)N * D * sizeof(ushort_t));
    ushort_t* W1lb    = (ushort_t*)take((size_t)D * D * sizeof(ushort_t));
    ushort_t* W1rb    = (ushort_t*)take((size_t)D * D * sizeof(ushort_t));
    ushort_t* W2lb    = (ushort_t*)take((size_t)D * D * sizeof(ushort_t));
    ushort_t* W2rb    = (ushort_t*)take((size_t)D * D * sizeof(ushort_t));
    (void)ws_size;
    (void)n_in;
    (void)out_size;

    hipMemsetAsync(bhist, 0, 1024 * sizeof(int), stream);

    int NB = (N + 255) / 256;
    int EB = (E + 4095) / 4096;
    long nx = (long)N * D;
    int CX = (int)((nx / 8 + 255) / 256);

    front_fused<<<EB + CX + 32, 256, 0, stream>>>(
        dst, bhist, E, EB, x, xb, nx, CX,
        W1l, W1r, W2l, W2r, W1lb, W1rb, W2lb, W2rb);
    bkt_scan<<<1, 512, 0, stream>>>(bhist, boff, bcur, row_ptr, N, E);
    bkt_scatter<<<EB, 256, 0, stream>>>(src, dst, bcur, ebuf, E);
    bkt_build<<<NB, 256, 0, stream>>>(ebuf, boff, row_ptr, csr, N);

    // half-split pipelined layers
    int H = ((N / 2 + 127) / 128) * 128;  // multiple of 128 (and of 8)
    if (H > N) H = N;
    int aggA = (H + 7) / 8;
    int aggB = (N - H + 7) / 8;
    int gemA = H / 128;
    int gemB = (N - H + 127) / 128;

    // layer 1: xb -> hb (relu, bf16)
    if (aggA) agg_k<<<aggA, 256, 0, stream>>>(xb, csr, row_ptr, aggb, 0, H);
    if (aggB + gemA)
        mid_fused<<<aggB + gemA, 256, 0, stream>>>(xb, csr, row_ptr, aggb,
                                                   W1lb, W1rb, b1, hb, nullptr,
                                                   H, N, 1, aggB);
    if (gemB) gemm_k<<<gemB, 256, 0, stream>>>(aggb, xb, W1lb, W1rb, b1,
                                               hb, nullptr, H, N, 1);

    // layer 2: hb -> out (f32)
    if (aggA) agg_k<<<aggA, 256, 0, stream>>>(hb, csr, row_ptr, aggb, 0, H);
    if (aggB + gemA)
        mid_fused<<<aggB + gemA, 256, 0, stream>>>(hb, csr, row_ptr, aggb,
                                                   W2lb, W2rb, b2, nullptr, out,
                                                   H, N, 0, aggB);
    if (gemB) gemm_k<<<gemB, 256, 0, stream>>>(aggb, hb, W2lb, W2rb, b2,
                                               nullptr, out, H, N, 0);
}

// Round 8
// 332.290 us; speedup vs baseline: 1.1044x; 1.1044x over previous
//
#include <hip/hip_runtime.h>
#include <cstdint>
#include <cstddef>

#define D 128

typedef unsigned short ushort_t;
typedef unsigned int uint_t;
typedef __attribute__((ext_vector_type(8))) short bf16x8;
typedef __attribute__((ext_vector_type(4))) float f32x4;

static __device__ __forceinline__ unsigned short f2bf(float f) {
    unsigned int u = __float_as_uint(f);
    u = (u + 0x7FFFu + ((u >> 16) & 1u)) >> 16;  // RNE
    return (unsigned short)u;
}
static __device__ __forceinline__ float bf_lo(uint_t v) {
    return __uint_as_float(v << 16);
}
static __device__ __forceinline__ float bf_hi(uint_t v) {
    return __uint_as_float(v & 0xFFFF0000u);
}

static __device__ __forceinline__ void cast8(const float* __restrict__ s,
                                             ushort_t* __restrict__ d) {
    float4 a = *(const float4*)s;
    float4 b = *(const float4*)(s + 4);
    uint4 o;
    o.x = (uint_t)f2bf(a.x) | ((uint_t)f2bf(a.y) << 16);
    o.y = (uint_t)f2bf(a.z) | ((uint_t)f2bf(a.w) << 16);
    o.z = (uint_t)f2bf(b.x) | ((uint_t)f2bf(b.y) << 16);
    o.w = (uint_t)f2bf(b.z) | ((uint_t)f2bf(b.w) << 16);
    *(uint4*)d = o;
}

// ================= fused front-end: bkt_hist + cast_x + cast_w =================

__global__ __launch_bounds__(256) void front_fused(
    const int* __restrict__ dst, int* __restrict__ bhist, int E, int EB,
    const float* __restrict__ x, ushort_t* __restrict__ xb, long nx, int CX,
    const float* __restrict__ W1l, const float* __restrict__ W1r,
    const float* __restrict__ W2l, const float* __restrict__ W2r,
    ushort_t* __restrict__ W1lb, ushort_t* __restrict__ W1rb,
    ushort_t* __restrict__ W2lb, ushort_t* __restrict__ W2rb,
    int* __restrict__ row_ptr, int N) {
    __shared__ int lh[512];
    int b = blockIdx.x, t = threadIdx.x;
    if (b == 0 && t == 0) row_ptr[N] = E;
    if (b < EB) {
        lh[t] = 0;
        lh[t + 256] = 0;
        __syncthreads();
        int base = b * 4096;
#pragma unroll
        for (int i = 0; i < 16; ++i) {
            int e = base + i * 256 + t;
            if (e < E) atomicAdd(&lh[dst[e] >> 8], 1);
        }
        __syncthreads();
        if (lh[t]) atomicAdd(&bhist[t], lh[t]);
        if (lh[t + 256]) atomicAdd(&bhist[t + 256], lh[t + 256]);
    } else if (b < EB + CX) {
        long i = ((long)(b - EB) * 256 + t) * 8;
        if (i < nx) cast8(x + i, xb + i);
    } else {
        int bb = b - EB - CX;  // 0..31; 8 blocks per weight array
        int arr = bb >> 3;
        long i = ((long)(bb & 7) * 256 + t) * 8;
        const float* s = (arr == 0) ? W1l : (arr == 1) ? W1r
                       : (arr == 2) ? W2l : W2r;
        ushort_t* d = (arr == 0) ? W1lb : (arr == 1) ? W1rb
                    : (arr == 2) ? W2lb : W2rb;
        cast8(s + i, d + i);
    }
}

// ================= CSR build (scan merged into scatter/build) =================
// bcur[512] is zero-initialized by the memset; each scatter block computes the
// global exclusive bucket offsets from bhist locally (512-wide LDS scan), so
// the 1-block bkt_scan kernel (whole-GPU idle bubble) is eliminated.

__global__ __launch_bounds__(256) void bkt_scatter2(const int* __restrict__ src,
                                                    const int* __restrict__ dst,
                                                    const int* __restrict__ bhist,
                                                    int* __restrict__ bcur,
                                                    int* __restrict__ ebuf, int E) {
    __shared__ int lh[512];
    __shared__ int lofs[512];
    __shared__ int gbs[512];
    __shared__ int tA[256];
    __shared__ int tB[256];
    __shared__ int sv[4096];
    __shared__ unsigned short sb[4096];
    int t = threadIdx.x;
    lh[t] = 0;
    lh[t + 256] = 0;
    __syncthreads();
    int base = blockIdx.x * 4096;
    unsigned pk[16];  // rank<<17 | bkt<<8 | dlocal
#pragma unroll
    for (int i = 0; i < 16; ++i) {
        int e = base + i * 256 + t;
        unsigned p = 0xFFFFFFFFu;
        if (e < E) {
            int d = dst[e];
            int bkt = d >> 8;
            int r = atomicAdd(&lh[bkt], 1);
            p = ((unsigned)r << 17) | ((unsigned)bkt << 8) | (unsigned)(d & 255);
        }
        pk[i] = p;
    }
    __syncthreads();
    // dual exclusive scans (2 buckets/thread): local hist + global bhist
    int a0 = lh[2 * t], a1 = lh[2 * t + 1];
    int g0 = bhist[2 * t], g1 = bhist[2 * t + 1];
    int ps = a0 + a1, gs = g0 + g1;
    tA[t] = ps;
    tB[t] = gs;
    __syncthreads();
    for (int off = 1; off < 256; off <<= 1) {
        int u1 = (t >= off) ? tA[t - off] : 0;
        int u2 = (t >= off) ? tB[t - off] : 0;
        __syncthreads();
        tA[t] += u1;
        tB[t] += u2;
        __syncthreads();
    }
    int lexb = tA[t] - ps;
    int gexb = tB[t] - gs;
    lofs[2 * t] = lexb;
    lofs[2 * t + 1] = lexb + a0;
    gbs[2 * t] = gexb;
    gbs[2 * t + 1] = gexb + g0;
    __syncthreads();
    // per-bucket global write base = global bucket offset + inter-block rank
    if (a0) gbs[2 * t] += atomicAdd(&bcur[2 * t], a0);
    if (a1) gbs[2 * t + 1] += atomicAdd(&bcur[2 * t + 1], a1);
    __syncthreads();
    // place edges bucket-sorted into LDS
#pragma unroll
    for (int i = 0; i < 16; ++i) {
        int e = base + i * 256 + t;
        if (e < E) {
            unsigned p = pk[i];
            int bkt = (p >> 8) & 511;
            int r = (int)(p >> 17);
            int pos = lofs[bkt] + r;
            sv[pos] = src[e] | ((int)(p & 255) << 20);
            sb[pos] = (unsigned short)bkt;
        }
    }
    __syncthreads();
    // coalesced write-out
    int cnt = min(E - base, 4096);
    for (int i = t; i < cnt; i += 256) {
        int b2 = sb[i];
        ebuf[gbs[b2] + (i - lofs[b2])] = sv[i];
    }
}

__global__ __launch_bounds__(256) void bkt_build2(const int* __restrict__ ebuf,
                                                  const int* __restrict__ bhist,
                                                  int* __restrict__ row_ptr,
                                                  int* __restrict__ csr, int N) {
    __shared__ int scn[512];
    __shared__ int tA[256];
    __shared__ int lcnt[256];
    __shared__ int lofs[256];
    __shared__ int lcur[256];
    int t = threadIdx.x;
    int b = blockIdx.x;
    int base = b << 8;
    // exclusive scan of bhist to get this bucket's edge range
    int g0 = bhist[2 * t], g1 = bhist[2 * t + 1];
    int gs = g0 + g1;
    tA[t] = gs;
    __syncthreads();
    for (int off = 1; off < 256; off <<= 1) {
        int u = (t >= off) ? tA[t - off] : 0;
        __syncthreads();
        tA[t] += u;
        __syncthreads();
    }
    int gexb = tA[t] - gs;
    scn[2 * t] = gexb;
    scn[2 * t + 1] = gexb + g0;
    lcnt[t] = 0;
    __syncthreads();
    int ebeg = scn[b];
    int eend = ebeg + bhist[b];
    for (int e = ebeg + t; e < eend; e += 256)
        atomicAdd(&lcnt[((unsigned)ebuf[e]) >> 20], 1);
    __syncthreads();
    int v = lcnt[t];
    lofs[t] = v;
    __syncthreads();
    for (int off = 1; off < 256; off <<= 1) {
        int u = (t >= off) ? lofs[t - off] : 0;
        __syncthreads();
        lofs[t] += u;
        __syncthreads();
    }
    int ex = lofs[t] - v;
    __syncthreads();
    lofs[t] = ex;
    lcur[t] = 0;
    if (base + t < N) row_ptr[base + t] = ebeg + ex;
    __syncthreads();
    for (int e = ebeg + t; e < eend; e += 256) {
        int u = ebuf[e];
        int d = ((unsigned)u) >> 20;
        int r = atomicAdd(&lcur[d], 1);
        csr[ebeg + lofs[d] + r] = u & 0xFFFFF;
    }
}

// ================= mean aggregation: 2 nodes per wave, chains interleaved ====
// Lean standalone kernel (no GEMM resource coupling). Per wave: two
// independent node chains; node-boundary latency legs (row_ptr -> csr) of one
// hide under the other's gathers; 8 uint4 (2KB) in flight per wave.

static __device__ __forceinline__ void acc8(uint4 v, float a[8]) {
    a[0] += bf_lo(v.x); a[1] += bf_hi(v.x);
    a[2] += bf_lo(v.y); a[3] += bf_hi(v.y);
    a[4] += bf_lo(v.z); a[5] += bf_hi(v.z);
    a[6] += bf_lo(v.w); a[7] += bf_hi(v.w);
}

static __device__ __forceinline__ uint4 grow(const ushort_t* __restrict__ xin,
                                             int s, int l16) {
    unsigned off = ((unsigned)s << 8) | ((unsigned)l16 << 4);  // bytes
    return *(const uint4*)((const char*)xin + off);
}

static __device__ __forceinline__ void agg_store(ushort_t* __restrict__ aggb,
                                                 int node, int l16,
                                                 const float a[8], int deg) {
    float inv = 1.0f / fmaxf((float)deg, 1.0f);
    uint4 o;
    o.x = (uint_t)f2bf(a[0] * inv) | ((uint_t)f2bf(a[1] * inv) << 16);
    o.y = (uint_t)f2bf(a[2] * inv) | ((uint_t)f2bf(a[3] * inv) << 16);
    o.z = (uint_t)f2bf(a[4] * inv) | ((uint_t)f2bf(a[5] * inv) << 16);
    o.w = (uint_t)f2bf(a[6] * inv) | ((uint_t)f2bf(a[7] * inv) << 16);
    unsigned off = ((unsigned)node << 8) | ((unsigned)l16 << 4);
    *(uint4*)((char*)aggb + off) = o;
}

__global__ __launch_bounds__(256) void agg_k2(const ushort_t* __restrict__ xin,
                                              const int* __restrict__ csr,
                                              const int* __restrict__ row_ptr,
                                              ushort_t* __restrict__ aggb, int N) {
    int wave = threadIdx.x >> 6;
    int lane = threadIdx.x & 63;
    int g = lane >> 4;    // row group 0..3
    int l16 = lane & 15;  // 16B segment within a 256B row
    int p = blockIdx.x * 8 + wave * 2;
    if (p >= N) return;
    int node0 = p;
    int node1 = min(p + 1, N - 1);  // tail duplicates node0 (benign rewrite)
    int b0 = row_ptr[node0];
    int deg0 = row_ptr[node0 + 1] - b0;
    int b1 = row_ptr[node1];
    int deg1 = row_ptr[node1 + 1] - b1;
    int d0 = min(deg0, 64), d1 = min(deg1, 64);
    int i0 = (deg0 > 0) ? csr[b0 + min(lane, deg0 - 1)] : 0;
    int i1 = (deg1 > 0) ? csr[b1 + min(lane, deg1 - 1)] : 0;
    int c0 = max(d0 - 1, 0), c1 = max(d1 - 1, 0);
    float a0[8] = {0.f, 0.f, 0.f, 0.f, 0.f, 0.f, 0.f, 0.f};
    float a1[8] = {0.f, 0.f, 0.f, 0.f, 0.f, 0.f, 0.f, 0.f};
    int mm = max(d0, d1);
    for (int e = 0; e < mm; e += 16) {
        bool do0 = (e < d0), do1 = (e < d1);  // wave-uniform
        uint4 v0[4], v1[4];
        if (do0) {
#pragma unroll
            for (int q = 0; q < 4; ++q) {
                int s = __shfl(i0, min(e + 4 * q + g, c0));
                v0[q] = grow(xin, s, l16);
            }
        }
        if (do1) {
#pragma unroll
            for (int q = 0; q < 4; ++q) {
                int s = __shfl(i1, min(e + 4 * q + g, c1));
                v1[q] = grow(xin, s, l16);
            }
        }
        if (do0) {
#pragma unroll
            for (int q = 0; q < 4; ++q)
                if (e + 4 * q + g < d0) acc8(v0[q], a0);
        }
        if (do1) {
#pragma unroll
            for (int q = 0; q < 4; ++q)
                if (e + 4 * q + g < d1) acc8(v1[q], a1);
        }
    }
    for (int e2 = 64; e2 < deg0; e2 += 4) {  // rare deg>64 fallback
        int s = csr[b0 + min(e2 + g, deg0 - 1)];
        uint4 v = grow(xin, s, l16);
        if (e2 + g < deg0) acc8(v, a0);
    }
    for (int e2 = 64; e2 < deg1; e2 += 4) {
        int s = csr[b1 + min(e2 + g, deg1 - 1)];
        uint4 v = grow(xin, s, l16);
        if (e2 + g < deg1) acc8(v, a1);
    }
#pragma unroll
    for (int i = 0; i < 8; ++i) {
        a0[i] += __shfl_xor(a0[i], 16);
        a1[i] += __shfl_xor(a1[i], 16);
        a0[i] += __shfl_xor(a0[i], 32);
        a1[i] += __shfl_xor(a1[i], 32);
    }
    if (g == 0) {
        agg_store(aggb, node0, l16, a0, deg0);
        agg_store(aggb, node1, l16, a1, deg1);
    }
}

// ================= MFMA GEMM (R1/R5-proven, byte-identical) =================

__global__ __launch_bounds__(256) void gemm_mfma(const ushort_t* __restrict__ Aagg,
                                                 const ushort_t* __restrict__ Ax,
                                                 const ushort_t* __restrict__ Wl,
                                                 const ushort_t* __restrict__ Wr,
                                                 const float* __restrict__ bias,
                                                 ushort_t* __restrict__ out_bf,
                                                 float* __restrict__ out_f32,
                                                 int N, int relu_bf) {
    __shared__ ushort_t sA[128 * 32];  // 8 KB
    __shared__ ushort_t sW[128 * 32];  // 8 KB
    int tid = threadIdx.x;
    int wave = tid >> 6, lane = tid & 63;
    int quad = lane >> 4, l15 = lane & 15;
    int wm = wave & 1, wc = wave >> 1;
    int n0 = blockIdx.x * 128;
    int sr = tid >> 2;
    int sseg = (tid & 3) * 8;

    f32x4 acc[4][4];
#pragma unroll
    for (int mt = 0; mt < 4; ++mt)
#pragma unroll
        for (int nt = 0; nt < 4; ++nt) acc[mt][nt] = (f32x4){0.f, 0.f, 0.f, 0.f};

    int ga0 = min(n0 + sr, N - 1);
    int ga1 = min(n0 + sr + 64, N - 1);

#pragma unroll
    for (int c = 0; c < 8; ++c) {
        const ushort_t* Ab = (c < 4) ? Aagg : Ax;
        const ushort_t* Wb = (c < 4) ? Wl : Wr;
        int koff = (c & 3) * 32 + sseg;
        bf16x8 va0 = *(const bf16x8*)(Ab + (size_t)ga0 * D + koff);
        bf16x8 va1 = *(const bf16x8*)(Ab + (size_t)ga1 * D + koff);
        bf16x8 vw0 = *(const bf16x8*)(Wb + (size_t)sr * D + koff);
        bf16x8 vw1 = *(const bf16x8*)(Wb + (size_t)(sr + 64) * D + koff);
        __syncthreads();
        *(bf16x8*)&sA[sr * 32 + sseg] = va0;
        *(bf16x8*)&sA[(sr + 64) * 32 + sseg] = va1;
        *(bf16x8*)&sW[sr * 32 + sseg] = vw0;
        *(bf16x8*)&sW[(sr + 64) * 32 + sseg] = vw1;
        __syncthreads();

        bf16x8 af[4], wf[4];
#pragma unroll
        for (int mt = 0; mt < 4; ++mt)
            af[mt] = *(const bf16x8*)&sA[(wm * 64 + mt * 16 + l15) * 32 + quad * 8];
#pragma unroll
        for (int nt = 0; nt < 4; ++nt)
            wf[nt] = *(const bf16x8*)&sW[(wc * 64 + nt * 16 + l15) * 32 + quad * 8];
#pragma unroll
        for (int mt = 0; mt < 4; ++mt)
#pragma unroll
            for (int nt = 0; nt < 4; ++nt)
                acc[mt][nt] = __builtin_amdgcn_mfma_f32_16x16x32_bf16(
                    af[mt], wf[nt], acc[mt][nt], 0, 0, 0);
    }

#pragma unroll
    for (int mt = 0; mt < 4; ++mt) {
#pragma unroll
        for (int nt = 0; nt < 4; ++nt) {
            int col = wc * 64 + nt * 16 + l15;
            float bv = bias[col];
#pragma unroll
            for (int reg = 0; reg < 4; ++reg) {
                int row = n0 + wm * 64 + mt * 16 + quad * 4 + reg;
                if (row < N) {
                    float v = acc[mt][nt][reg] + bv;
                    if (relu_bf) {
                        v = fmaxf(v, 0.f);
                        out_bf[(size_t)row * D + col] = f2bf(v);
                    } else {
                        out_f32[(size_t)row * D + col] = v;
                    }
                }
            }
        }
    }
}

// ================= launch =================

extern "C" void kernel_launch(void* const* d_in, const int* in_sizes, int n_in,
                              void* d_out, int out_size, void* d_ws, size_t ws_size,
                              hipStream_t stream) {
    const float* x   = (const float*)d_in[0];
    const int*   ei  = (const int*)d_in[1];
    const float* W1l = (const float*)d_in[2];
    const float* b1  = (const float*)d_in[3];
    const float* W1r = (const float*)d_in[4];
    const float* W2l = (const float*)d_in[5];
    const float* b2  = (const float*)d_in[6];
    const float* W2r = (const float*)d_in[7];
    float* out = (float*)d_out;

    int N = in_sizes[0] / D;
    int E = in_sizes[1] / 2;
    const int* src = ei;
    const int* dst = ei + E;

    char* ws = (char*)d_ws;
    size_t off = 0;
    auto take = [&](size_t bytes) -> char* {
        char* p = ws + off;
        off += (bytes + 255) & ~(size_t)255;
        return p;
    };
    int*      row_ptr = (int*)take((size_t)(N + 1) * sizeof(int));
    int*      bhist   = (int*)take((size_t)(512 + 512 + 513) * sizeof(int));
    int*      bcur    = bhist + 512;
    int*      ebuf    = (int*)take((size_t)E * sizeof(int));
    int*      csr     = (int*)take((size_t)E * sizeof(int));
    ushort_t* xb      = (ushort_t*)take((size_t)N * D * sizeof(ushort_t));
    ushort_t* hb      = (ushort_t*)take((size_t)N * D * sizeof(ushort_t));
    ushort_t* aggb    = (ushort_t*)take((size_t)N * D * sizeof(ushort_t));
    ushort_t* W1lb    = (ushort_t*)take((size_t)D * D * sizeof(ushort_t));
    ushort_t* W1rb    = (ushort_t*)take((size_t)D * D * sizeof(ushort_t));
    ushort_t* W2lb    = (ushort_t*)take((size_t)D * D * sizeof(ushort_t));
    ushort_t* W2rb    = (ushort_t*)take((size_t)D * D * sizeof(ushort_t));
    (void)ws_size;
    (void)n_in;
    (void)out_size;

    hipMemsetAsync(bhist, 0, 1024 * sizeof(int), stream);  // bhist + bcur

    int NB = (N + 255) / 256;
    int EB = (E + 4095) / 4096;
    long nx = (long)N * D;
    int CX = (int)((nx / 8 + 255) / 256);

    front_fused<<<EB + CX + 32, 256, 0, stream>>>(
        dst, bhist, E, EB, x, xb, nx, CX,
        W1l, W1r, W2l, W2r, W1lb, W1rb, W2lb, W2rb, row_ptr, N);
    bkt_scatter2<<<EB, 256, 0, stream>>>(src, dst, bhist, bcur, ebuf, E);
    bkt_build2<<<NB, 256, 0, stream>>>(ebuf, bhist, row_ptr, csr, N);

    int ablocks = (N + 7) / 8;
    int gblocks = (N + 127) / 128;

    agg_k2<<<ablocks, 256, 0, stream>>>(xb, csr, row_ptr, aggb, N);
    gemm_mfma<<<gblocks, 256, 0, stream>>>(aggb, xb, W1lb, W1rb, b1, hb, nullptr, N, 1);

    agg_k2<<<ablocks, 256, 0, stream>>>(hb, csr, row_ptr, aggb, N);
    gemm_mfma<<<gblocks, 256, 0, stream>>>(aggb, hb, W2lb, W2rb, b2, nullptr, out, N, 0);
}